// Round 4
// baseline (115.183 us; speedup 1.0000x reference)
//
#include <hip/hip_runtime.h>
#include <hip/hip_bf16.h>

typedef __hip_bfloat16 bf16;

// R14: 2-kernel pipeline done right. R13 post-mortem: dropping the WT4 repack
// cost ~7us because each wave-instr W load touched 16 scattered cache lines.
// R14 changes the GEMM decomposition so DIRECT W loads are 1KB-contiguous per
// wave-instruction (c4 = lane + 64j spans the whole wave over consecutive
// float4s; wave wv owns W rows wv*4+oi). Dot partials are wave-reduced with a
// 6-step shfl_xor butterfly into sred[8][48]; the 32KB red buffer and 16-way
// epilogue sums are gone (LDS 48KB -> ~19KB). Sniff lives in proj's head,
// w_sum in proj's tail (both cheap); out hoists the Wo dtype branch
// block-uniform. proj(512x256) -> out(512x256).
// flags f: 0=f32, 1=bf16, 2=all-zero; flags[13]=any bf16 (output dtype).

__device__ __forceinline__ float ldf(const void* p, int f, long idx) {
    if (f == 0) return ((const float*)p)[idx];
    if (f == 1) {
        unsigned int u = ((unsigned int)((const unsigned short*)p)[idx]) << 16;
        float r; __builtin_memcpy(&r, &u, 4); return r;
    }
    return 0.f;
}

// 4 consecutive elements starting at element idx (idx % 4 == 0).
__device__ __forceinline__ float4 ld4(const void* p, int f, long idx) {
    if (f == 0) return ((const float4*)p)[idx >> 2];
    if (f == 1) {
        const unsigned short* sp = (const unsigned short*)p + idx;
        unsigned int u0 = ((unsigned int)sp[0]) << 16;
        unsigned int u1 = ((unsigned int)sp[1]) << 16;
        unsigned int u2 = ((unsigned int)sp[2]) << 16;
        unsigned int u3 = ((unsigned int)sp[3]) << 16;
        float4 r;
        __builtin_memcpy(&r.x, &u0, 4); __builtin_memcpy(&r.y, &u1, 4);
        __builtin_memcpy(&r.z, &u2, 4); __builtin_memcpy(&r.w, &u3, 4);
        return r;
    }
    return make_float4(0.f, 0.f, 0.f, 0.f);
}

// parallel sniff of all 13 inputs -> sf[0..12]; 2 syncthreads.
__device__ __forceinline__ void sniff13(const void* const* ps, const int* ns,
                                        int tid, unsigned* mall, int* sf) {
    unsigned m = 0;
    for (int t = tid; t < 13 * 64; t += 256) {
        int p = t >> 6, j = t & 63;
        int n16 = ns[p] < 64 ? ns[p] : 64;
        if (j < n16) {
            unsigned short v = ((const unsigned short*)ps[p])[j];
            if (v != 0) m |= (1u << p);
        }
    }
    for (int t = tid; t < 13 * 32; t += 256) {
        int p = t >> 5, jp = t & 31;
        int n16 = ns[p] < 64 ? ns[p] : 64; int npair = n16 >> 1;
        if (jp < npair) {
            const unsigned short* u = (const unsigned short*)ps[p];
            unsigned short lo = u[2 * jp], hi = u[2 * jp + 1];
            int elo = (lo >> 7) & 0xFF, ehi = (hi >> 7) & 0xFF;
            bool lo_ok = (elo >= 64 && elo <= 190) || lo == 0;
            bool hi_ok = (ehi >= 64 && ehi <= 190) || hi == 0;
            if (!(lo_ok && hi_ok)) m |= (1u << (16 + p));
        }
    }
    #pragma unroll
    for (int off = 1; off < 64; off <<= 1) m |= __shfl_xor(m, off);
    if (tid == 0) *mall = 0;
    __syncthreads();
    if ((tid & 63) == 0) atomicOr(mall, m);
    __syncthreads();
    unsigned mm = *mall;
    if (tid < 13) {
        int f;
        if (!((mm >> tid) & 1)) f = 2;
        else f = ((mm >> (16 + tid)) & 1) ? 0 : 1;
        sf[tid] = f;
    }
    __syncthreads();
}

__device__ __forceinline__ float ldbias(const void* bk, const void* bv,
                                        const void* br, const int* sf, int o2) {
    if (o2 < 16) return ldf(bk, sf[6], o2);
    if (o2 < 32) return ldf(bv, sf[8], o2 - 16);
    if (o2 < 48) return ldf(br, sf[10], o2 - 32);
    return 0.f;
}

// proj: 8 rows/block (grid 512). GEMM: wave wv owns W rows wv*4+oi of each
// matrix; lane spans columns (c4 = lane + 64j -> 1KB contiguous W loads);
// wave-wide shfl butterfly reduces dots into sred[8][48]. Epilogue writes
// k_ws/r_ws + per-block partials blkS/blkKV; tail computes 2 w_sum entries;
// block 0 publishes flags.
__global__ __launch_bounds__(256) void proj_kernel(
    const void* x, const void* tw, const void* alpha, const void* beta,
    const void* gamma, const void* Wk, const void* bk, const void* Wv,
    const void* bv, const void* Wr, const void* br, const void* Wo,
    const void* bo,
    int n0, int n1, int n2, int n3, int n4, int n5, int n6, int n7,
    int n8, int n9, int n10, int n11, int n12,
    float* __restrict__ k_ws, float* __restrict__ r_ws,
    float* __restrict__ blkS, float* __restrict__ blkKV,
    float* __restrict__ w_sum, int* __restrict__ flags)
{
    __shared__ float xs[8 * 512];        // 16 KB
    __shared__ float sred[8][48];        // 1.5 KB full dot results
    __shared__ float kred[128], kvred[128];
    __shared__ float wsred[4];
    __shared__ int sf[16];
    __shared__ unsigned mall;
    int tid = threadIdx.x;
    const void* ps[13] = {x,tw,alpha,beta,gamma,Wk,bk,Wv,bv,Wr,br,Wo,bo};
    int ns[13] = {n0,n1,n2,n3,n4,n5,n6,n7,n8,n9,n10,n11,n12};
    sniff13(ps, ns, tid, &mall, sf);

    if (blockIdx.x == 0 && tid < 14) {
        if (tid == 13) {
            int any16 = 0;
            for (int j = 0; j < 13; ++j) if (sf[j] == 1) any16 = 1;
            flags[13] = any16;
        } else {
            flags[tid] = sf[tid];
        }
    }

    int row0 = blockIdx.x * 8;
    int b = row0 >> 10;
    int lt0 = row0 & 1023;
    int fx = sf[0];

    // ---- stage x rows (time-shifted first half) into LDS ----
    if (fx == 1) {
        const unsigned short* xp = (const unsigned short*)x;
        #pragma unroll
        for (int j = 0; j < 4; ++j) {
            int v = tid + 256 * j;
            int el = v * 4;
            int r = el >> 9, c = el & 511;
            int lt = lt0 + r - ((c < 256) ? 1 : 0);
            float4 f;
            if (lt < 0) f = make_float4(0.f, 0.f, 0.f, 0.f);
            else {
                const unsigned short* sp = xp + ((long)(b * 1024 + lt) * 512 + c);
                unsigned int u0 = ((unsigned int)sp[0]) << 16;
                unsigned int u1 = ((unsigned int)sp[1]) << 16;
                unsigned int u2 = ((unsigned int)sp[2]) << 16;
                unsigned int u3 = ((unsigned int)sp[3]) << 16;
                __builtin_memcpy(&f.x, &u0, 4); __builtin_memcpy(&f.y, &u1, 4);
                __builtin_memcpy(&f.z, &u2, 4); __builtin_memcpy(&f.w, &u3, 4);
            }
            reinterpret_cast<float4*>(xs)[v] = f;
        }
    } else {
        const float* xp = (const float*)x;
        #pragma unroll
        for (int j = 0; j < 4; ++j) {
            int v = tid + 256 * j;
            int el = v * 4;
            int r = el >> 9, c = el & 511;
            int lt = lt0 + r - ((c < 256) ? 1 : 0);
            float4 f;
            if (lt < 0) f = make_float4(0.f, 0.f, 0.f, 0.f);
            else f = *reinterpret_cast<const float4*>(xp + ((long)(b * 1024 + lt) * 512 + c));
            reinterpret_cast<float4*>(xs)[v] = f;
        }
    }
    __syncthreads();

    // ---- GEMM: 3 matrices x (4 rows/wave) x (8 x-rows) ----
    int lane = tid & 63, wv = tid >> 6;
    const float4* xs4 = reinterpret_cast<const float4*>(xs);
    const void* Wm[3] = {Wk, Wv, Wr};
    int fwm[3] = {sf[5], sf[7], sf[9]};
    #pragma unroll
    for (int m = 0; m < 3; ++m) {
        const void* Wp = Wm[m]; int fw = fwm[m];
        float acc[4][8];
        #pragma unroll
        for (int oi = 0; oi < 4; ++oi)
            #pragma unroll
            for (int r = 0; r < 8; ++r) acc[oi][r] = 0.f;

        if (fw == 0) {
            const float4* Wq = reinterpret_cast<const float4*>(Wp);
            #pragma unroll
            for (int j = 0; j < 2; ++j) {
                int c4 = lane + 64 * j;
                float4 xr[8];
                #pragma unroll
                for (int r = 0; r < 8; ++r) xr[r] = xs4[r * 128 + c4];
                #pragma unroll
                for (int oi = 0; oi < 4; ++oi) {
                    int row = wv * 4 + oi;
                    float4 wq = Wq[row * 128 + c4];   // 1KB contiguous per wave
                    #pragma unroll
                    for (int r = 0; r < 8; ++r)
                        acc[oi][r] += xr[r].x * wq.x + xr[r].y * wq.y +
                                      xr[r].z * wq.z + xr[r].w * wq.w;
                }
            }
        } else {
            #pragma unroll
            for (int j = 0; j < 2; ++j) {
                int c4 = lane + 64 * j;
                float4 xr[8];
                #pragma unroll
                for (int r = 0; r < 8; ++r) xr[r] = xs4[r * 128 + c4];
                #pragma unroll
                for (int oi = 0; oi < 4; ++oi) {
                    int row = wv * 4 + oi;
                    float4 wq = ld4(Wp, fw, (long)row * 512 + c4 * 4);
                    #pragma unroll
                    for (int r = 0; r < 8; ++r)
                        acc[oi][r] += xr[r].x * wq.x + xr[r].y * wq.y +
                                      xr[r].z * wq.z + xr[r].w * wq.w;
                }
            }
        }
        // wave-wide butterfly; static lane oi*8+r writes sred[r][m*16+wv*4+oi]
        #pragma unroll
        for (int oi = 0; oi < 4; ++oi) {
            #pragma unroll
            for (int r = 0; r < 8; ++r) {
                float a = acc[oi][r];
                a += __shfl_xor(a, 1);  a += __shfl_xor(a, 2);
                a += __shfl_xor(a, 4);  a += __shfl_xor(a, 8);
                a += __shfl_xor(a, 16); a += __shfl_xor(a, 32);
                if (lane == oi * 8 + r)
                    sred[r][m * 16 + wv * 4 + oi] = a;
            }
        }
    }
    __syncthreads();

    // ---- epilogue: k/exp, v partials, r ----
    #pragma unroll
    for (int it = 0; it < 2; ++it) {
        int idx = tid + 256 * it;        // < 512
        int o2 = idx & 63, r2 = idx >> 6;
        if (o2 < 48) {
            float s = ldbias(bk, bv, br, sf, o2) + sred[r2][o2];
            long a = (long)(lt0 + r2) * 64 + b * 16 + (o2 & 15);
            if (o2 < 16) {
                k_ws[a] = expf(fminf(fmaxf(s, -60.f), 30.f));
            } else if (o2 < 32) {
                int d = o2 - 16;
                float sk = ldbias(bk, bv, br, sf, d) + sred[r2][d];
                float kk = expf(fminf(fmaxf(sk, -60.f), 30.f));
                kred[d * 8 + r2] = kk;        // exclusive (d,r2) slot
                kvred[d * 8 + r2] = kk * s;   // s == v value here
            } else {
                r_ws[a] = s;
            }
        }
    }
    __syncthreads();
    if (tid < 16) {
        float sk = 0.f, skv = 0.f;
        #pragma unroll
        for (int r = 0; r < 8; ++r) { sk += kred[tid * 8 + r]; skv += kvred[tid * 8 + r]; }
        blkS[(long)blockIdx.x * 16 + tid] = sk;
        blkKV[(long)blockIdx.x * 16 + tid] = skv;
    }

    // ---- w_sum: 2 entries per block (u = 2*bid + g), 128 lanes each ----
    {
        int g = tid >> 7, l = tid & 127;
        int u = blockIdx.x * 2 + g;
        int n = 1024 - u;
        int ftw = sf[1], fbe = sf[3];
        float acc = 0.f;
        for (int s = l; s < n; s += 128)
            acc += ldf(tw, ftw, 1023 - s) * ldf(beta, fbe, u + s);
        #pragma unroll
        for (int off = 32; off > 0; off >>= 1) acc += __shfl_xor(acc, off);
        if ((tid & 63) == 0) wsred[tid >> 6] = acc;
        __syncthreads();
        if ((tid & 127) == 0)
            w_sum[u] = (wsred[g * 2] + wsred[g * 2 + 1]) * ldf(alpha, sf[2], u);
    }
}

// out: 8 rows/block (grid 512). Flags + w_sum precomputed by proj.
// cumk from blk partials + in-block k rows; kvmean from all 128 chunk partials.
__global__ __launch_bounds__(256) void out_kernel(
    const void* gamma, const void* Wo, const void* bo,
    const float* __restrict__ k_ws, const float* __restrict__ r_ws,
    const float* __restrict__ blkS, const float* __restrict__ blkKV,
    const float* __restrict__ w_sum, const int* __restrict__ flags,
    void* __restrict__ out)
{
    __shared__ float redc[256], redk[256];
    __shared__ float cums[16], kvm[16], kk8[8][16], rr8[8][16], rw[8][16];
    __shared__ int sfl[16];
    int tid = threadIdx.x;
    if (tid < 16) sfl[tid] = flags[tid];

    int row0 = blockIdx.x * 8;
    int b = row0 >> 10;
    int t0 = row0 & 1023;                 // 8-aligned
    int nch = t0 >> 3;                    // full 8-row chunks before t0
    long base = (long)b * 16;

    // ---- chunk-parallel partials: prefix-S over nch chunks, kv over all ----
    {
        int d = tid & 15, lane = tid >> 4;
        float pc = 0.f, pk = 0.f;
        for (int ch = lane; ch < nch; ch += 16) pc += blkS[((long)b * 128 + ch) * 16 + d];
        for (int ch = lane; ch < 128; ch += 16) pk += blkKV[((long)b * 128 + ch) * 16 + d];
        redc[tid] = pc; redk[tid] = pk;
    }
    // ---- this block's 8 rows of k and r into LDS ----
    if (tid < 128) {
        int rl = tid >> 4, dd = tid & 15;
        kk8[rl][dd] = k_ws[(long)(t0 + rl) * 64 + base + dd];
    } else {
        int tt = tid - 128; int rl = tt >> 4, dd = tt & 15;
        rr8[rl][dd] = r_ws[(long)(t0 + rl) * 64 + base + dd];
    }
    __syncthreads();
    if (tid < 16) {
        float c = 0.f, kv = 0.f;
        #pragma unroll
        for (int ln = 0; ln < 16; ++ln) { c += redc[ln * 16 + tid]; kv += redk[ln * 16 + tid]; }
        cums[tid] = c;
        kvm[tid] = kv * (1.0f / 1024.0f);
    }
    __syncthreads();

    // ---- per-row rwkv ----
    if (tid < 128) {
        int rl = tid >> 4, o = tid & 15;
        float ck = cums[o];
        for (int i = 0; i <= rl; ++i) ck += kk8[i][o];
        rw[rl][o] = rr8[rl][o] * w_sum[t0 + rl] * kvm[o] / (ck + 1e-8f);
    }
    __syncthreads();

    // ---- Wo dot + gamma + store (Wo branch hoisted block-uniform) ----
    int fWo = sfl[11], fbo = sfl[12], fga = sfl[4], any16 = sfl[13];
    if (fWo == 0) {
        const float4* Wq = reinterpret_cast<const float4*>(Wo);
        #pragma unroll
        for (int it = 0; it < 2; ++it) {
            int idx = tid + 256 * it;          // < 512
            int rl = idx >> 6, o = idx & 63;
            int t = t0 + rl;
            float acc = ldf(bo, fbo, o);
            #pragma unroll
            for (int j = 0; j < 4; ++j) {
                float4 w = Wq[o * 4 + j];
                acc += rw[rl][4 * j + 0] * w.x + rw[rl][4 * j + 1] * w.y +
                       rw[rl][4 * j + 2] * w.z + rw[rl][4 * j + 3] * w.w;
            }
            float val = acc * ldf(gamma, fga, t);
            long oa = (long)(row0 + rl) * 64 + o;
            if (any16) ((bf16*)out)[oa] = __float2bfloat16(val);
            else       ((float*)out)[oa] = val;
        }
    } else {
        #pragma unroll
        for (int it = 0; it < 2; ++it) {
            int idx = tid + 256 * it;
            int rl = idx >> 6, o = idx & 63;
            int t = t0 + rl;
            float acc = ldf(bo, fbo, o);
            #pragma unroll
            for (int j = 0; j < 4; ++j) {
                float4 w = ld4(Wo, fWo, (long)o * 16 + 4 * j);
                acc += rw[rl][4 * j + 0] * w.x + rw[rl][4 * j + 1] * w.y +
                       rw[rl][4 * j + 2] * w.z + rw[rl][4 * j + 3] * w.w;
            }
            float val = acc * ldf(gamma, fga, t);
            long oa = (long)(row0 + rl) * 64 + o;
            if (any16) ((bf16*)out)[oa] = __float2bfloat16(val);
            else       ((float*)out)[oa] = val;
        }
    }
}

extern "C" void kernel_launch(void* const* d_in, const int* in_sizes, int n_in,
                              void* d_out, int out_size, void* d_ws, size_t ws_size,
                              hipStream_t stream) {
    // insertion order (confirmed R4): x, time_w, time_alpha, time_beta,
    // time_gamma, Wk, bk, Wv, bv, Wr, br, Wo, bo
    const void* x     = d_in[0];
    const void* tw    = d_in[1];
    const void* alpha = d_in[2];
    const void* beta  = d_in[3];
    const void* gamma = d_in[4];
    const void* Wk    = d_in[5];
    const void* bk    = d_in[6];
    const void* Wv    = d_in[7];
    const void* bv    = d_in[8];
    const void* Wr    = d_in[9];
    const void* br    = d_in[10];
    const void* Wo    = d_in[11];
    const void* bo    = d_in[12];

    float* ws    = (float*)d_ws;
    float* k_ws  = ws;              // 65536  [t][b*16+d]  raw k
    float* r_ws  = ws + 65536;      // 65536
    float* blkS  = ws + 131072;     // 8192   [512][16] per-proj-block sum(k)
    float* blkKV = ws + 139264;     // 8192   [512][16] per-proj-block sum(k*v)
    float* w_sum = ws + 147456;     // 1024
    int*   flags = (int*)(ws + 148480);  // 16 ints

    proj_kernel<<<512, 256, 0, stream>>>(
        x, tw, alpha, beta, gamma, Wk, bk, Wv, bv, Wr, br, Wo, bo,
        in_sizes[0], in_sizes[1], in_sizes[2], in_sizes[3], in_sizes[4],
        in_sizes[5], in_sizes[6], in_sizes[7], in_sizes[8], in_sizes[9],
        in_sizes[10], in_sizes[11], in_sizes[12],
        k_ws, r_ws, blkS, blkKV, w_sum, flags);
    out_kernel<<<512, 256, 0, stream>>>(
        gamma, Wo, bo, k_ws, r_ws, blkS, blkKV, w_sum, flags, (void*)d_out);
}